// Round 7
// baseline (1255.621 us; speedup 1.0000x reference)
//
#include <hip/hip_runtime.h>

// SAGEConv (mean aggr, root weight, L2 normalize), fp32 in/out.
// R7: dst-range partition (8 buckets) -> XCD-local ELL fill -> gather (bf16)
//     -> MFMA GEMM over concat K=192 + L2norm. No deg/scan kernels.

typedef __attribute__((ext_vector_type(8))) short short8;   // 8 bf16 = 4 VGPRs
typedef __attribute__((ext_vector_type(4))) float floatx4;  // MFMA acc

constexpr int kNodes = 50000;
constexpr int kEdges = 800000;
constexpr int kF = 96;          // input features
constexpr int kH = 128;         // output features
constexpr int kEllW = 32;       // ELL width (Poisson(16): P(deg>32) ~ 1e-5)
constexpr int kCap = 131072;    // per-bucket partition capacity (mean 100K, +100sigma)
constexpr int kSpillCap = 4096;
constexpr int kBktRange = kNodes / 8;  // 6250

// workspace byte offsets
constexpr size_t kXhOff    = 0;                               // 9,600,000
constexpr size_t kPartOff  = 9600000;                         // 4 MB (dead after fill)
constexpr size_t kAggOff   = 9600000;                         // overlays part
constexpr size_t kWhOff    = 19200000;                        // 49,152
constexpr size_t kEllOff   = 19249152;                        // 3,200,000 (ushort)
constexpr size_t kCurOff   = 22449152;                        // 200,000
constexpr size_t kBktOff   = 22649152;                        // 32
constexpr size_t kSpcOff   = 22649184;                        // 4
constexpr size_t kSpillOff = 22649200;                        // 16,384

__device__ __forceinline__ unsigned pack2_bf16(float a, float b) {
  unsigned ua = __float_as_uint(a), ub = __float_as_uint(b);
  ua = (ua + 0x7fffu + ((ua >> 16) & 1u)) >> 16;   // RNE
  ub = (ub + 0x7fffu + ((ub >> 16) & 1u)) >> 16;
  return ua | (ub << 16);
}
__device__ __forceinline__ float bf_lo(unsigned u) { return __uint_as_float(u << 16); }
__device__ __forceinline__ float bf_hi(unsigned u) { return __uint_as_float(u & 0xffff0000u); }

// ELL insert shared by fill and the (never-in-practice) partition overflow path
__device__ __forceinline__ void ell_insert(int dst, int src, int* cursor,
                                           ushort* ell, unsigned* spill,
                                           int* spillCnt) {
  const int slot = atomicAdd(&cursor[dst], 1);
  if (slot < kEllW) {
    ell[(size_t)dst * kEllW + slot] = (ushort)src;
  } else {
    const int sp = atomicAdd(spillCnt, 1);
    if (sp < kSpillCap) spill[sp] = ((unsigned)dst << 16) | (unsigned)src;
  }
}

// --- prep: pack x -> bf16, pack W=[Wl|Wr] -> bf16, zero cursor/bkt/spillCnt --
__global__ void __launch_bounds__(256)
prep_kernel(const float* __restrict__ x, const float* __restrict__ Wl,
            const float* __restrict__ Wr, uint4* __restrict__ xh4,
            uint4* __restrict__ wh4, uint4* __restrict__ zero4) {
  constexpr int kCvt = kNodes * kF / 8;     // 600000
  constexpr int kWcvt = kH * 192 / 8;       // 3072
  constexpr int kZero = 12503;              // 50009 ints (cursor+bktCnt+spillCnt) padded
  const int i = blockIdx.x * 256 + threadIdx.x;
  if (i < kCvt) {
    const float4 v0 = reinterpret_cast<const float4*>(x)[i * 2];
    const float4 v1 = reinterpret_cast<const float4*>(x)[i * 2 + 1];
    uint4 o;
    o.x = pack2_bf16(v0.x, v0.y);
    o.y = pack2_bf16(v0.z, v0.w);
    o.z = pack2_bf16(v1.x, v1.y);
    o.w = pack2_bf16(v1.z, v1.w);
    xh4[i] = o;
  } else if (i < kCvt + kWcvt) {
    const int j = i - kCvt;
    const int row = j / 24, chunk = j % 24;
    const float* src = (chunk < 12) ? (Wl + (size_t)row * kF + chunk * 8)
                                    : (Wr + (size_t)row * kF + (chunk - 12) * 8);
    const float4 v0 = reinterpret_cast<const float4*>(src)[0];
    const float4 v1 = reinterpret_cast<const float4*>(src)[1];
    uint4 o;
    o.x = pack2_bf16(v0.x, v0.y);
    o.y = pack2_bf16(v0.z, v0.w);
    o.z = pack2_bf16(v1.x, v1.y);
    o.w = pack2_bf16(v1.z, v1.w);
    wh4[j] = o;
  } else if (i < kCvt + kWcvt + kZero) {
    zero4[i - kCvt - kWcvt] = make_uint4(0, 0, 0, 0);
  }
}

// --- partition: route (dst,src) pairs into 8 dst-range buckets ---------------
// Wave-aggregated: 8 ballots, <=8 atomics/wave, segment-coalesced stores.
__global__ void __launch_bounds__(256)
part_kernel(const int* __restrict__ ei, unsigned* __restrict__ part,
            int* __restrict__ bktCnt, int* __restrict__ cursor,
            ushort* __restrict__ ell, unsigned* __restrict__ spill,
            int* __restrict__ spillCnt) {
  const int i = blockIdx.x * 256 + threadIdx.x;  // 800000 exact
  const int src = ei[i];
  const int dst = ei[kEdges + i];
  const int b = dst / kBktRange;                 // 0..7
  const unsigned pair = ((unsigned)dst << 16) | (unsigned)src;
  const int lane = threadIdx.x & 63;
  const unsigned long long below = (1ull << lane) - 1ull;

#pragma unroll
  for (int b2 = 0; b2 < 8; ++b2) {
    const unsigned long long m = __ballot(b == b2);
    if (m != 0ull) {
      const int leader = __builtin_ctzll(m);
      int base = 0;
      if (lane == leader) base = atomicAdd(&bktCnt[b2], __popcll(m));
      base = __shfl(base, leader, 64);
      if (b == b2) {
        const int pos = base + __popcll(m & below);
        if (pos < kCap)
          part[(size_t)b2 * kCap + pos] = pair;
        else  // ~impossible (+100 sigma); stay correct
          ell_insert(dst, src, cursor, ell, spill, spillCnt);
      }
    }
  }
}

// --- fill: XCD-local ELL build. Block bid&7 handles bucket bid&7 -------------
__global__ void __launch_bounds__(256)
fillp_kernel(const unsigned* __restrict__ part, const int* __restrict__ bktCnt,
             int* __restrict__ cursor, ushort* __restrict__ ell,
             unsigned* __restrict__ spill, int* __restrict__ spillCnt) {
  const int b = blockIdx.x & 7;
  const int cnt = bktCnt[b];
  const int stride = (gridDim.x >> 3) * 256;
  for (int i = (blockIdx.x >> 3) * 256 + threadIdx.x; i < cnt; i += stride) {
    const unsigned pair = part[(size_t)b * kCap + i];
    ell_insert((int)(pair >> 16), (int)(pair & 0xffffu), cursor, ell, spill,
               spillCnt);
  }
}

// --- gather: mean of neighbor bf16 rows (ELL + spill) -> aggh (bf16) ---------
// One wave per node batch. 4 edge-slots x 12 lanes x uint4 (8 feats).
__global__ void __launch_bounds__(256)
gather_kernel(const uint4* __restrict__ xh4, const int* __restrict__ cursor,
              const ushort* __restrict__ ell, const unsigned* __restrict__ spill,
              const int* __restrict__ spillCnt, uint4* __restrict__ aggh4) {
  const int wave = threadIdx.x >> 6, lane = threadIdx.x & 63;
  const int slot = lane / 12;
  const int c = lane % 12;
  const bool gactive = lane < 48;
  const int sc = min(*spillCnt, kSpillCap);  // ~always 0

  for (int node = blockIdx.x * 4 + wave; node < kNodes; node += gridDim.x * 4) {
    const int deg = cursor[node];
    const int dmain = min(deg, kEllW);
    float a0 = 0.f, a1 = 0.f, a2 = 0.f, a3 = 0.f,
          a4 = 0.f, a5 = 0.f, a6 = 0.f, a7 = 0.f;
    const int nt = (dmain + 3) >> 2;
    for (int t = 0; t < nt; ++t) {
      const int idx = (t << 2) + slot;
      if (gactive && idx < dmain) {
        const int src = ell[(size_t)node * kEllW + idx];
        const uint4 v = xh4[(size_t)src * 12 + c];
        a0 += bf_lo(v.x); a1 += bf_hi(v.x);
        a2 += bf_lo(v.y); a3 += bf_hi(v.y);
        a4 += bf_lo(v.z); a5 += bf_hi(v.z);
        a6 += bf_lo(v.w); a7 += bf_hi(v.w);
      }
    }
    // spill edges (rare): slot-0 lanes accumulate, counted once
    for (int j = 0; j < sc; ++j) {
      const unsigned pr = spill[j];
      if ((int)(pr >> 16) == node && lane < 12) {
        const uint4 v = xh4[(size_t)(pr & 0xffffu) * 12 + c];
        a0 += bf_lo(v.x); a1 += bf_hi(v.x);
        a2 += bf_lo(v.y); a3 += bf_hi(v.y);
        a4 += bf_lo(v.z); a5 += bf_hi(v.z);
        a6 += bf_lo(v.w); a7 += bf_hi(v.w);
      }
    }
    // combine 4 slots -> lanes 0..11
    a0 += __shfl(a0, lane + 24, 64); a1 += __shfl(a1, lane + 24, 64);
    a2 += __shfl(a2, lane + 24, 64); a3 += __shfl(a3, lane + 24, 64);
    a4 += __shfl(a4, lane + 24, 64); a5 += __shfl(a5, lane + 24, 64);
    a6 += __shfl(a6, lane + 24, 64); a7 += __shfl(a7, lane + 24, 64);
    a0 += __shfl(a0, lane + 12, 64); a1 += __shfl(a1, lane + 12, 64);
    a2 += __shfl(a2, lane + 12, 64); a3 += __shfl(a3, lane + 12, 64);
    a4 += __shfl(a4, lane + 12, 64); a5 += __shfl(a5, lane + 12, 64);
    a6 += __shfl(a6, lane + 12, 64); a7 += __shfl(a7, lane + 12, 64);

    if (lane < 12) {
      const float inv = 1.0f / fmaxf((float)deg, 1.0f);
      uint4 o;
      o.x = pack2_bf16(a0 * inv, a1 * inv);
      o.y = pack2_bf16(a2 * inv, a3 * inv);
      o.z = pack2_bf16(a4 * inv, a5 * inv);
      o.w = pack2_bf16(a6 * inv, a7 * inv);
      aggh4[(size_t)node * 12 + c] = o;
    }
  }
}

// --- MFMA GEMM + bias + L2-normalize -----------------------------------------
// C[50000x128] = [agg | x]_bf16 @ Wh^T + b, row-normalized.
// A-frag: row=lane&15, k=(lane>>4)*8+j -> one uint4 of the packed row.
// D: col=lane&15, row=(lane>>4)*4+reg  (m89-verified mapping).
__global__ void __launch_bounds__(256)
mfma_kernel(const uint4* __restrict__ xh4, const uint4* __restrict__ aggh4,
            const uint4* __restrict__ wh4, const float* __restrict__ bl,
            float* __restrict__ out) {
  const int wave = threadIdx.x >> 6, lane = threadIdx.x & 63;
  const int tile = blockIdx.x * 4 + wave;
  if (tile >= kNodes / 16) return;  // 3125 tiles exact
  const int base = tile * 16;
  const int r = lane & 15, q = lane >> 4;

  const short8* aggS = reinterpret_cast<const short8*>(aggh4);
  const short8* xhS  = reinterpret_cast<const short8*>(xh4);
  const short8* whS  = reinterpret_cast<const short8*>(wh4);

  floatx4 acc[8] = {};
#pragma unroll
  for (int ks = 0; ks < 6; ++ks) {
    const short8* Ab = (ks < 3) ? aggS : xhS;
    const int chunk = (ks < 3 ? ks * 4 : (ks - 3) * 4) + q;
    const short8 a = Ab[(size_t)(base + r) * 12 + chunk];
#pragma unroll
    for (int cg = 0; cg < 8; ++cg) {
      const short8 b = whS[(cg * 16 + r) * 24 + ks * 4 + q];
      acc[cg] = __builtin_amdgcn_mfma_f32_16x16x32_bf16(a, b, acc[cg], 0, 0, 0);
    }
  }

  float p0 = 0.f, p1 = 0.f, p2 = 0.f, p3 = 0.f;
#pragma unroll
  for (int cg = 0; cg < 8; ++cg) {
    const float bb = bl[cg * 16 + r];
    acc[cg][0] += bb; acc[cg][1] += bb; acc[cg][2] += bb; acc[cg][3] += bb;
    p0 += acc[cg][0] * acc[cg][0];
    p1 += acc[cg][1] * acc[cg][1];
    p2 += acc[cg][2] * acc[cg][2];
    p3 += acc[cg][3] * acc[cg][3];
  }
#pragma unroll
  for (int off = 1; off < 16; off <<= 1) {
    p0 += __shfl_xor(p0, off, 64);
    p1 += __shfl_xor(p1, off, 64);
    p2 += __shfl_xor(p2, off, 64);
    p3 += __shfl_xor(p3, off, 64);
  }
  const float s0 = 1.0f / fmaxf(sqrtf(p0), 1e-12f);
  const float s1 = 1.0f / fmaxf(sqrtf(p1), 1e-12f);
  const float s2 = 1.0f / fmaxf(sqrtf(p2), 1e-12f);
  const float s3 = 1.0f / fmaxf(sqrtf(p3), 1e-12f);

#pragma unroll
  for (int cg = 0; cg < 8; ++cg) {
    const int col = cg * 16 + r;
    float* o = out + (size_t)(base + q * 4) * kH + col;
    o[0 * kH] = acc[cg][0] * s0;
    o[1 * kH] = acc[cg][1] * s1;
    o[2 * kH] = acc[cg][2] * s2;
    o[3 * kH] = acc[cg][3] * s3;
  }
}

extern "C" void kernel_launch(void* const* d_in, const int* in_sizes, int n_in,
                              void* d_out, int out_size, void* d_ws, size_t ws_size,
                              hipStream_t stream) {
  const int*   ei = (const int*)d_in[0];
  const float* x  = (const float*)d_in[1];
  const float* Wl = (const float*)d_in[2];
  const float* bl = (const float*)d_in[3];
  const float* Wr = (const float*)d_in[4];
  float* out = (float*)d_out;

  char* ws = (char*)d_ws;
  uint4*    xh4     = (uint4*)(ws + kXhOff);
  unsigned* part    = (unsigned*)(ws + kPartOff);
  uint4*    aggh4   = (uint4*)(ws + kAggOff);     // overlays part (dead by then)
  uint4*    wh4     = (uint4*)(ws + kWhOff);
  ushort*   ell     = (ushort*)(ws + kEllOff);
  int*      cursor  = (int*)(ws + kCurOff);
  int*      bktCnt  = (int*)(ws + kBktOff);
  int*      spillCnt= (int*)(ws + kSpcOff);
  unsigned* spill   = (unsigned*)(ws + kSpillOff);

  constexpr int kPrepTotal = kNodes * kF / 8 + kH * 192 / 8 + 12503;
  prep_kernel<<<(kPrepTotal + 255) / 256, 256, 0, stream>>>(
      x, Wl, Wr, xh4, wh4, (uint4*)(ws + kCurOff));

  part_kernel<<<kEdges / 256, 256, 0, stream>>>(ei, part, bktCnt, cursor, ell,
                                                spill, spillCnt);
  fillp_kernel<<<3072, 256, 0, stream>>>(part, bktCnt, cursor, ell, spill,
                                         spillCnt);

  gather_kernel<<<3125, 256, 0, stream>>>(xh4, cursor, ell, spill, spillCnt,
                                          aggh4);

  constexpr int tiles = kNodes / 16;                 // 3125
  mfma_kernel<<<(tiles + 3) / 4, 256, 0, stream>>>(xh4, aggh4, wh4, bl, out);
}

// Round 8
// 120.255 us; speedup vs baseline: 10.4413x; 10.4413x over previous
//
#include <hip/hip_runtime.h>

// SAGEConv (mean aggr, root weight, L2 normalize), fp32 in/out.
// R8: XCD-filtered direct ELL fill (no partition, no deg/scan) -> gather (bf16)
//     -> MFMA GEMM over concat K=192 + L2norm. 4 launches.

typedef __attribute__((ext_vector_type(8))) short short8;   // 8 bf16 = 4 VGPRs
typedef __attribute__((ext_vector_type(4))) float floatx4;  // MFMA acc

constexpr int kNodes = 50000;
constexpr int kEdges = 800000;
constexpr int kF = 96;          // input features
constexpr int kH = 128;         // output features
constexpr int kEllW = 32;       // ELL width (Poisson(16): P(deg>32) ~ 1e-5)
constexpr int kSpillCap = 4096;
constexpr int kBktRange = kNodes / 8;  // 6250 nodes per XCD-group

// workspace byte offsets
constexpr size_t kXhOff    = 0;                               // 9,600,000
constexpr size_t kAggOff   = 9600000;                         // 9,600,000
constexpr size_t kWhOff    = 19200000;                        // 49,152
constexpr size_t kEllOff   = 19249152;                        // 3,200,000 (ushort)
constexpr size_t kCurOff   = 22449152;                        // 200,000 (cursor)
constexpr size_t kSpcOff   = 22649152;                        // 4 (spillCnt, right after cursor)
constexpr size_t kSpillOff = 22649168;                        // 16,384

__device__ __forceinline__ unsigned pack2_bf16(float a, float b) {
  unsigned ua = __float_as_uint(a), ub = __float_as_uint(b);
  ua = (ua + 0x7fffu + ((ua >> 16) & 1u)) >> 16;   // RNE
  ub = (ub + 0x7fffu + ((ub >> 16) & 1u)) >> 16;
  return ua | (ub << 16);
}
__device__ __forceinline__ float bf_lo(unsigned u) { return __uint_as_float(u << 16); }
__device__ __forceinline__ float bf_hi(unsigned u) { return __uint_as_float(u & 0xffff0000u); }

__device__ __forceinline__ void ell_insert(int dst, int src, int* cursor,
                                           ushort* ell, unsigned* spill,
                                           int* spillCnt) {
  const int slot = atomicAdd(&cursor[dst], 1);
  if (slot < kEllW) {
    ell[(size_t)dst * kEllW + slot] = (ushort)src;
  } else {
    const int sp = atomicAdd(spillCnt, 1);
    if (sp < kSpillCap) spill[sp] = ((unsigned)dst << 16) | (unsigned)src;
  }
}

// --- prep: pack x -> bf16, pack W=[Wl|Wr] -> bf16, zero cursor+spillCnt ------
__global__ void __launch_bounds__(256)
prep_kernel(const float* __restrict__ x, const float* __restrict__ Wl,
            const float* __restrict__ Wr, uint4* __restrict__ xh4,
            uint4* __restrict__ wh4, uint4* __restrict__ zero4) {
  constexpr int kCvt = kNodes * kF / 8;     // 600000
  constexpr int kWcvt = kH * 192 / 8;       // 3072
  constexpr int kZero = 12501;              // 50004 ints >= cursor(50000)+spillCnt
  const int i = blockIdx.x * 256 + threadIdx.x;
  if (i < kCvt) {
    const float4 v0 = reinterpret_cast<const float4*>(x)[i * 2];
    const float4 v1 = reinterpret_cast<const float4*>(x)[i * 2 + 1];
    uint4 o;
    o.x = pack2_bf16(v0.x, v0.y);
    o.y = pack2_bf16(v0.z, v0.w);
    o.z = pack2_bf16(v1.x, v1.y);
    o.w = pack2_bf16(v1.z, v1.w);
    xh4[i] = o;
  } else if (i < kCvt + kWcvt) {
    const int j = i - kCvt;
    const int row = j / 24, chunk = j % 24;
    const float* src = (chunk < 12) ? (Wl + (size_t)row * kF + chunk * 8)
                                    : (Wr + (size_t)row * kF + (chunk - 12) * 8);
    const float4 v0 = reinterpret_cast<const float4*>(src)[0];
    const float4 v1 = reinterpret_cast<const float4*>(src)[1];
    uint4 o;
    o.x = pack2_bf16(v0.x, v0.y);
    o.y = pack2_bf16(v0.z, v0.w);
    o.z = pack2_bf16(v1.x, v1.y);
    o.w = pack2_bf16(v1.z, v1.w);
    wh4[j] = o;
  } else if (i < kCvt + kWcvt + kZero) {
    zero4[i - kCvt - kWcvt] = make_uint4(0, 0, 0, 0);
  }
}

// --- fill: XCD-filtered direct ELL build -------------------------------------
// Group g = blockIdx&7 scans ALL edges, commits only dst in its 6250-node
// range: cursor/ELL traffic stays in one XCD's L2 (blockIdx%8 ~ XCD heuristic;
// wrong mapping only costs speed, not correctness). 8x redundant ei reads are
// cheap (51 MB). 4 edges/thread for read ILP.
__global__ void __launch_bounds__(256)
fill_kernel(const int* __restrict__ ei, int* __restrict__ cursor,
            ushort* __restrict__ ell, unsigned* __restrict__ spill,
            int* __restrict__ spillCnt) {
  const int g = blockIdx.x & 7;
  const int chunk = blockIdx.x >> 3;           // 0..781
  const int lo = g * kBktRange, hi = lo + kBktRange;
  const int base = chunk * 1024 + threadIdx.x;
  int d[4];
#pragma unroll
  for (int k = 0; k < 4; ++k) {
    const int e = base + k * 256;
    d[k] = (e < kEdges) ? ei[kEdges + e] : -1;
  }
#pragma unroll
  for (int k = 0; k < 4; ++k) {
    if (d[k] >= lo && d[k] < hi) {
      const int e = base + k * 256;
      ell_insert(d[k], ei[e], cursor, ell, spill, spillCnt);
    }
  }
}

// --- gather: mean of neighbor bf16 rows (ELL + spill) -> aggh (bf16) ---------
// One wave per node; node ranges XCD-matched to fill's dst ranges (warm ELL).
// 4 edge-slots x 12 lanes x uint4 (8 feats).
__global__ void __launch_bounds__(256)
gather_kernel(const uint4* __restrict__ xh4, const int* __restrict__ cursor,
              const ushort* __restrict__ ell, const unsigned* __restrict__ spill,
              const int* __restrict__ spillCnt, uint4* __restrict__ aggh4) {
  const int wave = threadIdx.x >> 6, lane = threadIdx.x & 63;
  const int slot = lane / 12;
  const int c = lane % 12;
  const bool gactive = lane < 48;
  const int sc = min(*spillCnt, kSpillCap);  // ~always 0
  const int g = blockIdx.x & 7;
  const int j = blockIdx.x >> 3;
  const int stride = (gridDim.x >> 3) * 4;
  const int hi = (g + 1) * kBktRange;

  for (int node = g * kBktRange + j * 4 + wave; node < hi; node += stride) {
    const int deg = cursor[node];
    const int dmain = min(deg, kEllW);
    float a0 = 0.f, a1 = 0.f, a2 = 0.f, a3 = 0.f,
          a4 = 0.f, a5 = 0.f, a6 = 0.f, a7 = 0.f;
    const int nt = (dmain + 3) >> 2;
    for (int t = 0; t < nt; ++t) {
      const int idx = (t << 2) + slot;
      if (gactive && idx < dmain) {
        const int src = ell[(size_t)node * kEllW + idx];
        const uint4 v = xh4[(size_t)src * 12 + c];
        a0 += bf_lo(v.x); a1 += bf_hi(v.x);
        a2 += bf_lo(v.y); a3 += bf_hi(v.y);
        a4 += bf_lo(v.z); a5 += bf_hi(v.z);
        a6 += bf_lo(v.w); a7 += bf_hi(v.w);
      }
    }
    // spill edges (rare): chunk lanes accumulate directly
    for (int jj = 0; jj < sc; ++jj) {
      const unsigned pr = spill[jj];
      if ((int)(pr >> 16) == node && lane < 12) {
        const uint4 v = xh4[(size_t)(pr & 0xffffu) * 12 + c];
        a0 += bf_lo(v.x); a1 += bf_hi(v.x);
        a2 += bf_lo(v.y); a3 += bf_hi(v.y);
        a4 += bf_lo(v.z); a5 += bf_hi(v.z);
        a6 += bf_lo(v.w); a7 += bf_hi(v.w);
      }
    }
    // combine 4 slots -> lanes 0..11
    a0 += __shfl(a0, lane + 24, 64); a1 += __shfl(a1, lane + 24, 64);
    a2 += __shfl(a2, lane + 24, 64); a3 += __shfl(a3, lane + 24, 64);
    a4 += __shfl(a4, lane + 24, 64); a5 += __shfl(a5, lane + 24, 64);
    a6 += __shfl(a6, lane + 24, 64); a7 += __shfl(a7, lane + 24, 64);
    a0 += __shfl(a0, lane + 12, 64); a1 += __shfl(a1, lane + 12, 64);
    a2 += __shfl(a2, lane + 12, 64); a3 += __shfl(a3, lane + 12, 64);
    a4 += __shfl(a4, lane + 12, 64); a5 += __shfl(a5, lane + 12, 64);
    a6 += __shfl(a6, lane + 12, 64); a7 += __shfl(a7, lane + 12, 64);

    if (lane < 12) {
      const float inv = 1.0f / fmaxf((float)deg, 1.0f);
      uint4 o;
      o.x = pack2_bf16(a0 * inv, a1 * inv);
      o.y = pack2_bf16(a2 * inv, a3 * inv);
      o.z = pack2_bf16(a4 * inv, a5 * inv);
      o.w = pack2_bf16(a6 * inv, a7 * inv);
      aggh4[(size_t)node * 12 + c] = o;
    }
  }
}

// --- MFMA GEMM + bias + L2-normalize -----------------------------------------
// C[50000x128] = [agg | x]_bf16 @ Wh^T + b, row-normalized.
// A-frag: row=lane&15, k=(lane>>4)*8+j -> one uint4 of the packed row.
// D: col=lane&15, row=(lane>>4)*4+reg  (m89-verified mapping).
__global__ void __launch_bounds__(256)
mfma_kernel(const uint4* __restrict__ xh4, const uint4* __restrict__ aggh4,
            const uint4* __restrict__ wh4, const float* __restrict__ bl,
            float* __restrict__ out) {
  const int wave = threadIdx.x >> 6, lane = threadIdx.x & 63;
  const int tile = blockIdx.x * 4 + wave;
  if (tile >= kNodes / 16) return;  // 3125 tiles exact
  const int base = tile * 16;
  const int r = lane & 15, q = lane >> 4;

  const short8* aggS = reinterpret_cast<const short8*>(aggh4);
  const short8* xhS  = reinterpret_cast<const short8*>(xh4);
  const short8* whS  = reinterpret_cast<const short8*>(wh4);

  floatx4 acc[8] = {};
#pragma unroll
  for (int ks = 0; ks < 6; ++ks) {
    const short8* Ab = (ks < 3) ? aggS : xhS;
    const int chunk = (ks < 3 ? ks * 4 : (ks - 3) * 4) + q;
    const short8 a = Ab[(size_t)(base + r) * 12 + chunk];
#pragma unroll
    for (int cg = 0; cg < 8; ++cg) {
      const short8 b = whS[(cg * 16 + r) * 24 + ks * 4 + q];
      acc[cg] = __builtin_amdgcn_mfma_f32_16x16x32_bf16(a, b, acc[cg], 0, 0, 0);
    }
  }

  float p0 = 0.f, p1 = 0.f, p2 = 0.f, p3 = 0.f;
#pragma unroll
  for (int cg = 0; cg < 8; ++cg) {
    const float bb = bl[cg * 16 + r];
    acc[cg][0] += bb; acc[cg][1] += bb; acc[cg][2] += bb; acc[cg][3] += bb;
    p0 += acc[cg][0] * acc[cg][0];
    p1 += acc[cg][1] * acc[cg][1];
    p2 += acc[cg][2] * acc[cg][2];
    p3 += acc[cg][3] * acc[cg][3];
  }
#pragma unroll
  for (int off = 1; off < 16; off <<= 1) {
    p0 += __shfl_xor(p0, off, 64);
    p1 += __shfl_xor(p1, off, 64);
    p2 += __shfl_xor(p2, off, 64);
    p3 += __shfl_xor(p3, off, 64);
  }
  const float s0 = 1.0f / fmaxf(sqrtf(p0), 1e-12f);
  const float s1 = 1.0f / fmaxf(sqrtf(p1), 1e-12f);
  const float s2 = 1.0f / fmaxf(sqrtf(p2), 1e-12f);
  const float s3 = 1.0f / fmaxf(sqrtf(p3), 1e-12f);

#pragma unroll
  for (int cg = 0; cg < 8; ++cg) {
    const int col = cg * 16 + r;
    float* o = out + (size_t)(base + q * 4) * kH + col;
    o[0 * kH] = acc[cg][0] * s0;
    o[1 * kH] = acc[cg][1] * s1;
    o[2 * kH] = acc[cg][2] * s2;
    o[3 * kH] = acc[cg][3] * s3;
  }
}

extern "C" void kernel_launch(void* const* d_in, const int* in_sizes, int n_in,
                              void* d_out, int out_size, void* d_ws, size_t ws_size,
                              hipStream_t stream) {
  const int*   ei = (const int*)d_in[0];
  const float* x  = (const float*)d_in[1];
  const float* Wl = (const float*)d_in[2];
  const float* bl = (const float*)d_in[3];
  const float* Wr = (const float*)d_in[4];
  float* out = (float*)d_out;

  char* ws = (char*)d_ws;
  uint4*    xh4      = (uint4*)(ws + kXhOff);
  uint4*    aggh4    = (uint4*)(ws + kAggOff);
  uint4*    wh4      = (uint4*)(ws + kWhOff);
  ushort*   ell      = (ushort*)(ws + kEllOff);
  int*      cursor   = (int*)(ws + kCurOff);
  int*      spillCnt = (int*)(ws + kSpcOff);
  unsigned* spill    = (unsigned*)(ws + kSpillOff);

  constexpr int kPrepTotal = kNodes * kF / 8 + kH * 192 / 8 + 12501;
  prep_kernel<<<(kPrepTotal + 255) / 256, 256, 0, stream>>>(
      x, Wl, Wr, xh4, wh4, (uint4*)(ws + kCurOff));

  // 782 edge-chunks x 8 XCD groups
  fill_kernel<<<782 * 8, 256, 0, stream>>>(ei, cursor, ell, spill, spillCnt);

  // 391 node-chunks x 8 XCD groups (nodes XCD-matched to fill's dst ranges)
  gather_kernel<<<391 * 8, 256, 0, stream>>>(xh4, cursor, ell, spill, spillCnt,
                                             aggh4);

  constexpr int tiles = kNodes / 16;                 // 3125
  mfma_kernel<<<(tiles + 3) / 4, 256, 0, stream>>>(xh4, aggh4, wh4, bl, out);
}

// Round 9
// 112.658 us; speedup vs baseline: 11.1455x; 1.0674x over previous
//
#include <hip/hip_runtime.h>

// SAGEConv (mean aggr, root weight, L2 normalize), fp32 in/out.
// R9: gather ELL loop fully unrolled (8 fixed iters, 2-phase: index loads then
//     gathers) for 8-deep MLP. Rest identical to R8.

typedef __attribute__((ext_vector_type(8))) short short8;   // 8 bf16 = 4 VGPRs
typedef __attribute__((ext_vector_type(4))) float floatx4;  // MFMA acc

constexpr int kNodes = 50000;
constexpr int kEdges = 800000;
constexpr int kF = 96;          // input features
constexpr int kH = 128;         // output features
constexpr int kEllW = 32;       // ELL width (Poisson(16): P(deg>32) ~ 1e-5)
constexpr int kSpillCap = 4096;
constexpr int kBktRange = kNodes / 8;  // 6250 nodes per XCD-group

// workspace byte offsets
constexpr size_t kXhOff    = 0;                               // 9,600,000
constexpr size_t kAggOff   = 9600000;                         // 9,600,000
constexpr size_t kWhOff    = 19200000;                        // 49,152
constexpr size_t kEllOff   = 19249152;                        // 3,200,000 (ushort)
constexpr size_t kCurOff   = 22449152;                        // 200,000 (cursor)
constexpr size_t kSpcOff   = 22649152;                        // 4 (spillCnt)
constexpr size_t kSpillOff = 22649168;                        // 16,384

__device__ __forceinline__ unsigned pack2_bf16(float a, float b) {
  unsigned ua = __float_as_uint(a), ub = __float_as_uint(b);
  ua = (ua + 0x7fffu + ((ua >> 16) & 1u)) >> 16;   // RNE
  ub = (ub + 0x7fffu + ((ub >> 16) & 1u)) >> 16;
  return ua | (ub << 16);
}
__device__ __forceinline__ float bf_lo(unsigned u) { return __uint_as_float(u << 16); }
__device__ __forceinline__ float bf_hi(unsigned u) { return __uint_as_float(u & 0xffff0000u); }

__device__ __forceinline__ void ell_insert(int dst, int src, int* cursor,
                                           ushort* ell, unsigned* spill,
                                           int* spillCnt) {
  const int slot = atomicAdd(&cursor[dst], 1);
  if (slot < kEllW) {
    ell[(size_t)dst * kEllW + slot] = (ushort)src;
  } else {
    const int sp = atomicAdd(spillCnt, 1);
    if (sp < kSpillCap) spill[sp] = ((unsigned)dst << 16) | (unsigned)src;
  }
}

// --- prep: pack x -> bf16, pack W=[Wl|Wr] -> bf16, zero cursor+spillCnt ------
__global__ void __launch_bounds__(256)
prep_kernel(const float* __restrict__ x, const float* __restrict__ Wl,
            const float* __restrict__ Wr, uint4* __restrict__ xh4,
            uint4* __restrict__ wh4, uint4* __restrict__ zero4) {
  constexpr int kCvt = kNodes * kF / 8;     // 600000
  constexpr int kWcvt = kH * 192 / 8;       // 3072
  constexpr int kZero = 12501;              // 50004 ints >= cursor(50000)+spillCnt
  const int i = blockIdx.x * 256 + threadIdx.x;
  if (i < kCvt) {
    const float4 v0 = reinterpret_cast<const float4*>(x)[i * 2];
    const float4 v1 = reinterpret_cast<const float4*>(x)[i * 2 + 1];
    uint4 o;
    o.x = pack2_bf16(v0.x, v0.y);
    o.y = pack2_bf16(v0.z, v0.w);
    o.z = pack2_bf16(v1.x, v1.y);
    o.w = pack2_bf16(v1.z, v1.w);
    xh4[i] = o;
  } else if (i < kCvt + kWcvt) {
    const int j = i - kCvt;
    const int row = j / 24, chunk = j % 24;
    const float* src = (chunk < 12) ? (Wl + (size_t)row * kF + chunk * 8)
                                    : (Wr + (size_t)row * kF + (chunk - 12) * 8);
    const float4 v0 = reinterpret_cast<const float4*>(src)[0];
    const float4 v1 = reinterpret_cast<const float4*>(src)[1];
    uint4 o;
    o.x = pack2_bf16(v0.x, v0.y);
    o.y = pack2_bf16(v0.z, v0.w);
    o.z = pack2_bf16(v1.x, v1.y);
    o.w = pack2_bf16(v1.z, v1.w);
    wh4[j] = o;
  } else if (i < kCvt + kWcvt + kZero) {
    zero4[i - kCvt - kWcvt] = make_uint4(0, 0, 0, 0);
  }
}

// --- fill: XCD-filtered direct ELL build (identical to R8) -------------------
__global__ void __launch_bounds__(256)
fill_kernel(const int* __restrict__ ei, int* __restrict__ cursor,
            ushort* __restrict__ ell, unsigned* __restrict__ spill,
            int* __restrict__ spillCnt) {
  const int g = blockIdx.x & 7;
  const int chunk = blockIdx.x >> 3;           // 0..781
  const int lo = g * kBktRange, hi = lo + kBktRange;
  const int base = chunk * 1024 + threadIdx.x;
  int d[4];
#pragma unroll
  for (int k = 0; k < 4; ++k) {
    const int e = base + k * 256;
    d[k] = (e < kEdges) ? ei[kEdges + e] : -1;
  }
#pragma unroll
  for (int k = 0; k < 4; ++k) {
    if (d[k] >= lo && d[k] < hi) {
      const int e = base + k * 256;
      ell_insert(d[k], ei[e], cursor, ell, spill, spillCnt);
    }
  }
}

// --- gather: mean of neighbor bf16 rows (ELL + spill) -> aggh (bf16) ---------
// One wave per node; node ranges XCD-matched to fill's dst ranges.
// R9: fixed 8-iter full unroll, 2-phase (8 index loads -> 8 gathers) for ILP.
__global__ void __launch_bounds__(256)
gather_kernel(const uint4* __restrict__ xh4, const int* __restrict__ cursor,
              const ushort* __restrict__ ell, const unsigned* __restrict__ spill,
              const int* __restrict__ spillCnt, uint4* __restrict__ aggh4) {
  const int wave = threadIdx.x >> 6, lane = threadIdx.x & 63;
  const int slot = lane / 12;
  const int c = lane % 12;
  const bool gactive = lane < 48;
  const int sc = min(*spillCnt, kSpillCap);  // ~always 0
  const int g = blockIdx.x & 7;
  const int j = blockIdx.x >> 3;
  const int stride = (gridDim.x >> 3) * 4;
  const int hi = (g + 1) * kBktRange;

  for (int node = g * kBktRange + j * 4 + wave; node < hi; node += stride) {
    const int deg = cursor[node];
    const int dmain = min(deg, kEllW);
    const ushort* __restrict__ erow = ell + (size_t)node * kEllW;
    float a0 = 0.f, a1 = 0.f, a2 = 0.f, a3 = 0.f,
          a4 = 0.f, a5 = 0.f, a6 = 0.f, a7 = 0.f;

    // phase 1: 8 independent predicated index loads
    int srcs[8];
#pragma unroll
    for (int t = 0; t < 8; ++t) {
      const int idx = (t << 2) + slot;
      srcs[t] = (gactive && idx < dmain) ? (int)erow[idx] : -1;
    }
    // phase 2: 8 independent predicated 16B gathers
#pragma unroll
    for (int t = 0; t < 8; ++t) {
      if (srcs[t] >= 0) {
        const uint4 v = xh4[(size_t)srcs[t] * 12 + c];
        a0 += bf_lo(v.x); a1 += bf_hi(v.x);
        a2 += bf_lo(v.y); a3 += bf_hi(v.y);
        a4 += bf_lo(v.z); a5 += bf_hi(v.z);
        a6 += bf_lo(v.w); a7 += bf_hi(v.w);
      }
    }
    // spill edges (rare)
    for (int jj = 0; jj < sc; ++jj) {
      const unsigned pr = spill[jj];
      if ((int)(pr >> 16) == node && lane < 12) {
        const uint4 v = xh4[(size_t)(pr & 0xffffu) * 12 + c];
        a0 += bf_lo(v.x); a1 += bf_hi(v.x);
        a2 += bf_lo(v.y); a3 += bf_hi(v.y);
        a4 += bf_lo(v.z); a5 += bf_hi(v.z);
        a6 += bf_lo(v.w); a7 += bf_hi(v.w);
      }
    }
    // combine 4 slots -> lanes 0..11
    a0 += __shfl(a0, lane + 24, 64); a1 += __shfl(a1, lane + 24, 64);
    a2 += __shfl(a2, lane + 24, 64); a3 += __shfl(a3, lane + 24, 64);
    a4 += __shfl(a4, lane + 24, 64); a5 += __shfl(a5, lane + 24, 64);
    a6 += __shfl(a6, lane + 24, 64); a7 += __shfl(a7, lane + 24, 64);
    a0 += __shfl(a0, lane + 12, 64); a1 += __shfl(a1, lane + 12, 64);
    a2 += __shfl(a2, lane + 12, 64); a3 += __shfl(a3, lane + 12, 64);
    a4 += __shfl(a4, lane + 12, 64); a5 += __shfl(a5, lane + 12, 64);
    a6 += __shfl(a6, lane + 12, 64); a7 += __shfl(a7, lane + 12, 64);

    if (lane < 12) {
      const float inv = 1.0f / fmaxf((float)deg, 1.0f);
      uint4 o;
      o.x = pack2_bf16(a0 * inv, a1 * inv);
      o.y = pack2_bf16(a2 * inv, a3 * inv);
      o.z = pack2_bf16(a4 * inv, a5 * inv);
      o.w = pack2_bf16(a6 * inv, a7 * inv);
      aggh4[(size_t)node * 12 + c] = o;
    }
  }
}

// --- MFMA GEMM + bias + L2-normalize (identical to R8) -----------------------
__global__ void __launch_bounds__(256)
mfma_kernel(const uint4* __restrict__ xh4, const uint4* __restrict__ aggh4,
            const uint4* __restrict__ wh4, const float* __restrict__ bl,
            float* __restrict__ out) {
  const int wave = threadIdx.x >> 6, lane = threadIdx.x & 63;
  const int tile = blockIdx.x * 4 + wave;
  if (tile >= kNodes / 16) return;  // 3125 tiles exact
  const int base = tile * 16;
  const int r = lane & 15, q = lane >> 4;

  const short8* aggS = reinterpret_cast<const short8*>(aggh4);
  const short8* xhS  = reinterpret_cast<const short8*>(xh4);
  const short8* whS  = reinterpret_cast<const short8*>(wh4);

  floatx4 acc[8] = {};
#pragma unroll
  for (int ks = 0; ks < 6; ++ks) {
    const short8* Ab = (ks < 3) ? aggS : xhS;
    const int chunk = (ks < 3 ? ks * 4 : (ks - 3) * 4) + q;
    const short8 a = Ab[(size_t)(base + r) * 12 + chunk];
#pragma unroll
    for (int cg = 0; cg < 8; ++cg) {
      const short8 b = whS[(cg * 16 + r) * 24 + ks * 4 + q];
      acc[cg] = __builtin_amdgcn_mfma_f32_16x16x32_bf16(a, b, acc[cg], 0, 0, 0);
    }
  }

  float p0 = 0.f, p1 = 0.f, p2 = 0.f, p3 = 0.f;
#pragma unroll
  for (int cg = 0; cg < 8; ++cg) {
    const float bb = bl[cg * 16 + r];
    acc[cg][0] += bb; acc[cg][1] += bb; acc[cg][2] += bb; acc[cg][3] += bb;
    p0 += acc[cg][0] * acc[cg][0];
    p1 += acc[cg][1] * acc[cg][1];
    p2 += acc[cg][2] * acc[cg][2];
    p3 += acc[cg][3] * acc[cg][3];
  }
#pragma unroll
  for (int off = 1; off < 16; off <<= 1) {
    p0 += __shfl_xor(p0, off, 64);
    p1 += __shfl_xor(p1, off, 64);
    p2 += __shfl_xor(p2, off, 64);
    p3 += __shfl_xor(p3, off, 64);
  }
  const float s0 = 1.0f / fmaxf(sqrtf(p0), 1e-12f);
  const float s1 = 1.0f / fmaxf(sqrtf(p1), 1e-12f);
  const float s2 = 1.0f / fmaxf(sqrtf(p2), 1e-12f);
  const float s3 = 1.0f / fmaxf(sqrtf(p3), 1e-12f);

#pragma unroll
  for (int cg = 0; cg < 8; ++cg) {
    const int col = cg * 16 + r;
    float* o = out + (size_t)(base + q * 4) * kH + col;
    o[0 * kH] = acc[cg][0] * s0;
    o[1 * kH] = acc[cg][1] * s1;
    o[2 * kH] = acc[cg][2] * s2;
    o[3 * kH] = acc[cg][3] * s3;
  }
}

extern "C" void kernel_launch(void* const* d_in, const int* in_sizes, int n_in,
                              void* d_out, int out_size, void* d_ws, size_t ws_size,
                              hipStream_t stream) {
  const int*   ei = (const int*)d_in[0];
  const float* x  = (const float*)d_in[1];
  const float* Wl = (const float*)d_in[2];
  const float* bl = (const float*)d_in[3];
  const float* Wr = (const float*)d_in[4];
  float* out = (float*)d_out;

  char* ws = (char*)d_ws;
  uint4*    xh4      = (uint4*)(ws + kXhOff);
  uint4*    aggh4    = (uint4*)(ws + kAggOff);
  uint4*    wh4      = (uint4*)(ws + kWhOff);
  ushort*   ell      = (ushort*)(ws + kEllOff);
  int*      cursor   = (int*)(ws + kCurOff);
  int*      spillCnt = (int*)(ws + kSpcOff);
  unsigned* spill    = (unsigned*)(ws + kSpillOff);

  constexpr int kPrepTotal = kNodes * kF / 8 + kH * 192 / 8 + 12501;
  prep_kernel<<<(kPrepTotal + 255) / 256, 256, 0, stream>>>(
      x, Wl, Wr, xh4, wh4, (uint4*)(ws + kCurOff));

  // 782 edge-chunks x 8 XCD groups
  fill_kernel<<<782 * 8, 256, 0, stream>>>(ei, cursor, ell, spill, spillCnt);

  // 391 node-chunks x 8 XCD groups (nodes XCD-matched to fill's dst ranges)
  gather_kernel<<<391 * 8, 256, 0, stream>>>(xh4, cursor, ell, spill, spillCnt,
                                             aggh4);

  constexpr int tiles = kNodes / 16;                 // 3125
  mfma_kernel<<<(tiles + 3) / 4, 256, 0, stream>>>(xh4, aggh4, wh4, bl, out);
}

// Round 10
// 111.681 us; speedup vs baseline: 11.2430x; 1.0087x over previous
//
#include <hip/hip_runtime.h>

// SAGEConv (mean aggr, root weight, L2 normalize), fp32 in/out.
// R10: memset cursor -> mega(prep || XCD-filtered ELL fill) -> gather(2 nodes/wave)
//      -> MFMA GEMM over concat K=192 + L2norm.

typedef __attribute__((ext_vector_type(8))) short short8;   // 8 bf16 = 4 VGPRs
typedef __attribute__((ext_vector_type(4))) float floatx4;  // MFMA acc

constexpr int kNodes = 50000;
constexpr int kEdges = 800000;
constexpr int kF = 96;          // input features
constexpr int kH = 128;         // output features
constexpr int kEllW = 32;       // ELL width (Poisson(16): P(deg>32) ~ 1e-5)
constexpr int kSpillCap = 4096;
constexpr int kBktRange = kNodes / 8;  // 6250 nodes per XCD-group

// workspace byte offsets
constexpr size_t kXhOff    = 0;                               // 9,600,000
constexpr size_t kAggOff   = 9600000;                         // 9,600,000
constexpr size_t kWhOff    = 19200000;                        // 49,152
constexpr size_t kEllOff   = 19249152;                        // 3,200,000 (ushort)
constexpr size_t kCurOff   = 22449152;                        // 200,000 (cursor)
constexpr size_t kSpcOff   = 22649152;                        // 4 (spillCnt)
constexpr size_t kSpillOff = 22649168;                        // 16,384

// grid split for the mega kernel
constexpr int kFillBlocks = 782 * 8;                          // 6256
constexpr int kPrepItems  = kNodes * kF / 8 + kH * 192 / 8;   // 603072
constexpr int kPrepBlocks = (kPrepItems + 255) / 256;         // 2356

__device__ __forceinline__ unsigned pack2_bf16(float a, float b) {
  unsigned ua = __float_as_uint(a), ub = __float_as_uint(b);
  ua = (ua + 0x7fffu + ((ua >> 16) & 1u)) >> 16;   // RNE
  ub = (ub + 0x7fffu + ((ub >> 16) & 1u)) >> 16;
  return ua | (ub << 16);
}
__device__ __forceinline__ float bf_lo(unsigned u) { return __uint_as_float(u << 16); }
__device__ __forceinline__ float bf_hi(unsigned u) { return __uint_as_float(u & 0xffff0000u); }

__device__ __forceinline__ void ell_insert(int dst, int src, int* cursor,
                                           ushort* ell, unsigned* spill,
                                           int* spillCnt) {
  const int slot = atomicAdd(&cursor[dst], 1);
  if (slot < kEllW) {
    ell[(size_t)dst * kEllW + slot] = (ushort)src;
  } else {
    const int sp = atomicAdd(spillCnt, 1);
    if (sp < kSpillCap) spill[sp] = ((unsigned)dst << 16) | (unsigned)src;
  }
}

// --- mega: blocks [0,kFillBlocks) do XCD-filtered ELL fill; rest do bf16 prep.
// fill (latency/atomic-bound) and prep (BW-bound) are data-independent ->
// co-running overlaps the two regimes. cursor/spillCnt pre-zeroed by memset.
__global__ void __launch_bounds__(256)
mega_kernel(const int* __restrict__ ei, const float* __restrict__ x,
            const float* __restrict__ Wl, const float* __restrict__ Wr,
            uint4* __restrict__ xh4, uint4* __restrict__ wh4,
            int* __restrict__ cursor, ushort* __restrict__ ell,
            unsigned* __restrict__ spill, int* __restrict__ spillCnt) {
  if (blockIdx.x < kFillBlocks) {
    // ---- fill part (identical logic to R9) ----
    const int g = blockIdx.x & 7;
    const int chunk = blockIdx.x >> 3;           // 0..781
    const int lo = g * kBktRange, hi = lo + kBktRange;
    const int base = chunk * 1024 + threadIdx.x;
    int d[4];
#pragma unroll
    for (int k = 0; k < 4; ++k) {
      const int e = base + k * 256;
      d[k] = (e < kEdges) ? ei[kEdges + e] : -1;
    }
#pragma unroll
    for (int k = 0; k < 4; ++k) {
      if (d[k] >= lo && d[k] < hi) {
        const int e = base + k * 256;
        ell_insert(d[k], ei[e], cursor, ell, spill, spillCnt);
      }
    }
    return;
  }
  // ---- prep part ----
  constexpr int kCvt = kNodes * kF / 8;     // 600000
  const int i = (blockIdx.x - kFillBlocks) * 256 + threadIdx.x;
  if (i < kCvt) {
    const float4 v0 = reinterpret_cast<const float4*>(x)[i * 2];
    const float4 v1 = reinterpret_cast<const float4*>(x)[i * 2 + 1];
    uint4 o;
    o.x = pack2_bf16(v0.x, v0.y);
    o.y = pack2_bf16(v0.z, v0.w);
    o.z = pack2_bf16(v1.x, v1.y);
    o.w = pack2_bf16(v1.z, v1.w);
    xh4[i] = o;
  } else if (i < kPrepItems) {
    const int j = i - kCvt;
    const int row = j / 24, chunk = j % 24;
    const float* src = (chunk < 12) ? (Wl + (size_t)row * kF + chunk * 8)
                                    : (Wr + (size_t)row * kF + (chunk - 12) * 8);
    const float4 v0 = reinterpret_cast<const float4*>(src)[0];
    const float4 v1 = reinterpret_cast<const float4*>(src)[1];
    uint4 o;
    o.x = pack2_bf16(v0.x, v0.y);
    o.y = pack2_bf16(v0.z, v0.w);
    o.z = pack2_bf16(v1.x, v1.y);
    o.w = pack2_bf16(v1.z, v1.w);
    wh4[j] = o;
  }
}

// --- gather: mean of neighbor bf16 rows (ELL + spill) -> aggh (bf16) ---------
// R10: TWO nodes per wave -> 16 index loads + 16 independent gathers in
// flight per lane. Node ranges XCD-matched to fill's dst ranges.
__global__ void __launch_bounds__(256)
gather_kernel(const uint4* __restrict__ xh4, const int* __restrict__ cursor,
              const ushort* __restrict__ ell, const unsigned* __restrict__ spill,
              const int* __restrict__ spillCnt, uint4* __restrict__ aggh4) {
  const int wave = threadIdx.x >> 6, lane = threadIdx.x & 63;
  const int slot = lane / 12;
  const int c = lane % 12;
  const bool gactive = lane < 48;
  const int sc = min(*spillCnt, kSpillCap);  // ~always 0
  const int g = blockIdx.x & 7;
  const int j = blockIdx.x >> 3;
  const int stride = (gridDim.x >> 3) * 8;   // 8 nodes per block per iter
  const int hi = (g + 1) * kBktRange;

  for (int nA = g * kBktRange + j * 8 + wave * 2; nA < hi; nA += stride) {
    const int nB = nA + 1;
    const bool hasB = nB < hi;
    const int degA = cursor[nA];
    const int degB = hasB ? cursor[nB] : 0;
    const int dmA = min(degA, kEllW);
    const int dmB = min(degB, kEllW);
    const ushort* __restrict__ erowA = ell + (size_t)nA * kEllW;
    const ushort* __restrict__ erowB = ell + (size_t)nB * kEllW;

    float a0 = 0.f, a1 = 0.f, a2 = 0.f, a3 = 0.f,
          a4 = 0.f, a5 = 0.f, a6 = 0.f, a7 = 0.f;
    float b0 = 0.f, b1 = 0.f, b2 = 0.f, b3 = 0.f,
          b4 = 0.f, b5 = 0.f, b6 = 0.f, b7 = 0.f;

    // phase 1: 16 independent predicated index loads
    int sA[8], sB[8];
#pragma unroll
    for (int t = 0; t < 8; ++t) {
      const int idx = (t << 2) + slot;
      sA[t] = (gactive && idx < dmA) ? (int)erowA[idx] : -1;
      sB[t] = (gactive && idx < dmB) ? (int)erowB[idx] : -1;
    }
    // phase 2: 16 independent predicated 16B gathers
#pragma unroll
    for (int t = 0; t < 8; ++t) {
      if (sA[t] >= 0) {
        const uint4 v = xh4[(size_t)sA[t] * 12 + c];
        a0 += bf_lo(v.x); a1 += bf_hi(v.x);
        a2 += bf_lo(v.y); a3 += bf_hi(v.y);
        a4 += bf_lo(v.z); a5 += bf_hi(v.z);
        a6 += bf_lo(v.w); a7 += bf_hi(v.w);
      }
      if (sB[t] >= 0) {
        const uint4 v = xh4[(size_t)sB[t] * 12 + c];
        b0 += bf_lo(v.x); b1 += bf_hi(v.x);
        b2 += bf_lo(v.y); b3 += bf_hi(v.y);
        b4 += bf_lo(v.z); b5 += bf_hi(v.z);
        b6 += bf_lo(v.w); b7 += bf_hi(v.w);
      }
    }
    // spill edges (rare)
    for (int jj = 0; jj < sc; ++jj) {
      const unsigned pr = spill[jj];
      const int pd = (int)(pr >> 16);
      if (lane < 12 && (pd == nA || (hasB && pd == nB))) {
        const uint4 v = xh4[(size_t)(pr & 0xffffu) * 12 + c];
        if (pd == nA) {
          a0 += bf_lo(v.x); a1 += bf_hi(v.x);
          a2 += bf_lo(v.y); a3 += bf_hi(v.y);
          a4 += bf_lo(v.z); a5 += bf_hi(v.z);
          a6 += bf_lo(v.w); a7 += bf_hi(v.w);
        } else {
          b0 += bf_lo(v.x); b1 += bf_hi(v.x);
          b2 += bf_lo(v.y); b3 += bf_hi(v.y);
          b4 += bf_lo(v.z); b5 += bf_hi(v.z);
          b6 += bf_lo(v.w); b7 += bf_hi(v.w);
        }
      }
    }
    // combine 4 slots -> lanes 0..11 (node A)
    a0 += __shfl(a0, lane + 24, 64); a1 += __shfl(a1, lane + 24, 64);
    a2 += __shfl(a2, lane + 24, 64); a3 += __shfl(a3, lane + 24, 64);
    a4 += __shfl(a4, lane + 24, 64); a5 += __shfl(a5, lane + 24, 64);
    a6 += __shfl(a6, lane + 24, 64); a7 += __shfl(a7, lane + 24, 64);
    a0 += __shfl(a0, lane + 12, 64); a1 += __shfl(a1, lane + 12, 64);
    a2 += __shfl(a2, lane + 12, 64); a3 += __shfl(a3, lane + 12, 64);
    a4 += __shfl(a4, lane + 12, 64); a5 += __shfl(a5, lane + 12, 64);
    a6 += __shfl(a6, lane + 12, 64); a7 += __shfl(a7, lane + 12, 64);
    // (node B)
    b0 += __shfl(b0, lane + 24, 64); b1 += __shfl(b1, lane + 24, 64);
    b2 += __shfl(b2, lane + 24, 64); b3 += __shfl(b3, lane + 24, 64);
    b4 += __shfl(b4, lane + 24, 64); b5 += __shfl(b5, lane + 24, 64);
    b6 += __shfl(b6, lane + 24, 64); b7 += __shfl(b7, lane + 24, 64);
    b0 += __shfl(b0, lane + 12, 64); b1 += __shfl(b1, lane + 12, 64);
    b2 += __shfl(b2, lane + 12, 64); b3 += __shfl(b3, lane + 12, 64);
    b4 += __shfl(b4, lane + 12, 64); b5 += __shfl(b5, lane + 12, 64);
    b6 += __shfl(b6, lane + 12, 64); b7 += __shfl(b7, lane + 12, 64);

    if (lane < 12) {
      const float invA = 1.0f / fmaxf((float)degA, 1.0f);
      uint4 o;
      o.x = pack2_bf16(a0 * invA, a1 * invA);
      o.y = pack2_bf16(a2 * invA, a3 * invA);
      o.z = pack2_bf16(a4 * invA, a5 * invA);
      o.w = pack2_bf16(a6 * invA, a7 * invA);
      aggh4[(size_t)nA * 12 + c] = o;
      if (hasB) {
        const float invB = 1.0f / fmaxf((float)degB, 1.0f);
        uint4 p;
        p.x = pack2_bf16(b0 * invB, b1 * invB);
        p.y = pack2_bf16(b2 * invB, b3 * invB);
        p.z = pack2_bf16(b4 * invB, b5 * invB);
        p.w = pack2_bf16(b6 * invB, b7 * invB);
        aggh4[(size_t)nB * 12 + c] = p;
      }
    }
  }
}

// --- MFMA GEMM + bias + L2-normalize (identical to R9) -----------------------
__global__ void __launch_bounds__(256)
mfma_kernel(const uint4* __restrict__ xh4, const uint4* __restrict__ aggh4,
            const uint4* __restrict__ wh4, const float* __restrict__ bl,
            float* __restrict__ out) {
  const int wave = threadIdx.x >> 6, lane = threadIdx.x & 63;
  const int tile = blockIdx.x * 4 + wave;
  if (tile >= kNodes / 16) return;  // 3125 tiles exact
  const int base = tile * 16;
  const int r = lane & 15, q = lane >> 4;

  const short8* aggS = reinterpret_cast<const short8*>(aggh4);
  const short8* xhS  = reinterpret_cast<const short8*>(xh4);
  const short8* whS  = reinterpret_cast<const short8*>(wh4);

  floatx4 acc[8] = {};
#pragma unroll
  for (int ks = 0; ks < 6; ++ks) {
    const short8* Ab = (ks < 3) ? aggS : xhS;
    const int chunk = (ks < 3 ? ks * 4 : (ks - 3) * 4) + q;
    const short8 a = Ab[(size_t)(base + r) * 12 + chunk];
#pragma unroll
    for (int cg = 0; cg < 8; ++cg) {
      const short8 b = whS[(cg * 16 + r) * 24 + ks * 4 + q];
      acc[cg] = __builtin_amdgcn_mfma_f32_16x16x32_bf16(a, b, acc[cg], 0, 0, 0);
    }
  }

  float p0 = 0.f, p1 = 0.f, p2 = 0.f, p3 = 0.f;
#pragma unroll
  for (int cg = 0; cg < 8; ++cg) {
    const float bb = bl[cg * 16 + r];
    acc[cg][0] += bb; acc[cg][1] += bb; acc[cg][2] += bb; acc[cg][3] += bb;
    p0 += acc[cg][0] * acc[cg][0];
    p1 += acc[cg][1] * acc[cg][1];
    p2 += acc[cg][2] * acc[cg][2];
    p3 += acc[cg][3] * acc[cg][3];
  }
#pragma unroll
  for (int off = 1; off < 16; off <<= 1) {
    p0 += __shfl_xor(p0, off, 64);
    p1 += __shfl_xor(p1, off, 64);
    p2 += __shfl_xor(p2, off, 64);
    p3 += __shfl_xor(p3, off, 64);
  }
  const float s0 = 1.0f / fmaxf(sqrtf(p0), 1e-12f);
  const float s1 = 1.0f / fmaxf(sqrtf(p1), 1e-12f);
  const float s2 = 1.0f / fmaxf(sqrtf(p2), 1e-12f);
  const float s3 = 1.0f / fmaxf(sqrtf(p3), 1e-12f);

#pragma unroll
  for (int cg = 0; cg < 8; ++cg) {
    const int col = cg * 16 + r;
    float* o = out + (size_t)(base + q * 4) * kH + col;
    o[0 * kH] = acc[cg][0] * s0;
    o[1 * kH] = acc[cg][1] * s1;
    o[2 * kH] = acc[cg][2] * s2;
    o[3 * kH] = acc[cg][3] * s3;
  }
}

extern "C" void kernel_launch(void* const* d_in, const int* in_sizes, int n_in,
                              void* d_out, int out_size, void* d_ws, size_t ws_size,
                              hipStream_t stream) {
  const int*   ei = (const int*)d_in[0];
  const float* x  = (const float*)d_in[1];
  const float* Wl = (const float*)d_in[2];
  const float* bl = (const float*)d_in[3];
  const float* Wr = (const float*)d_in[4];
  float* out = (float*)d_out;

  char* ws = (char*)d_ws;
  uint4*    xh4      = (uint4*)(ws + kXhOff);
  uint4*    aggh4    = (uint4*)(ws + kAggOff);
  uint4*    wh4      = (uint4*)(ws + kWhOff);
  ushort*   ell      = (ushort*)(ws + kEllOff);
  int*      cursor   = (int*)(ws + kCurOff);
  int*      spillCnt = (int*)(ws + kSpcOff);
  unsigned* spill    = (unsigned*)(ws + kSpillOff);

  // zero cursor (200000 B) + spillCnt (4 B, adjacent)
  hipMemsetAsync(ws + kCurOff, 0, 200008, stream);

  mega_kernel<<<kFillBlocks + kPrepBlocks, 256, 0, stream>>>(
      ei, x, Wl, Wr, xh4, wh4, cursor, ell, spill, spillCnt);

  // 391 node-pair-chunks x 8 XCD groups, 2 nodes/wave
  gather_kernel<<<391 * 8, 256, 0, stream>>>(xh4, cursor, ell, spill, spillCnt,
                                             aggh4);

  constexpr int tiles = kNodes / 16;                 // 3125
  mfma_kernel<<<(tiles + 3) / 4, 256, 0, stream>>>(xh4, aggh4, wh4, bl, out);
}